// Round 6
// baseline (323.578 us; speedup 1.0000x reference)
//
#include <hip/hip_runtime.h>
#include <stdint.h>
#include <math.h>

#define L_SEQ  4096
#define DMODEL 768
#define NHEADS 12
#define DKH    64
// 0.125 (=1/sqrt(64)) * log2(e): folded into Qp so p = exp2(S') needs no extra mul
#define QSCALE 0.18033688011112042f

typedef _Float16 f16;
typedef __attribute__((ext_vector_type(8))) _Float16 half8;
typedef __attribute__((ext_vector_type(4))) _Float16 half4;
typedef __attribute__((ext_vector_type(4))) float f32x4;
typedef __attribute__((ext_vector_type(16))) float f32x16;
typedef __attribute__((ext_vector_type(4))) unsigned int uint4v;

#define MFMA16(a, b, c) __builtin_amdgcn_mfma_f32_16x16x32_f16(a, b, c, 0, 0, 0)
#define MFMA32(a, b, c) __builtin_amdgcn_mfma_f32_32x32x16_f16(a, b, c, 0, 0, 0)

#define NE ((size_t)L_SEQ * DMODEL)      // 3,145,728
#define WE ((size_t)DMODEL * DMODEL)     // 589,824

static __device__ __forceinline__ unsigned int pack2(float a, float b) {
  return __builtin_bit_cast(unsigned int, __builtin_amdgcn_cvt_pkrtz(a, b));
}

// ---------------------------------------------------------------------------
// cvt_all: q,k,v (3*NE fp32) and Wq,Wk,Wv,Wo (4*WE fp32) -> f16. (R5 frozen)
// ---------------------------------------------------------------------------
__global__ __launch_bounds__(256)
void cvt_all(const float* __restrict__ q, const float* __restrict__ k,
             const float* __restrict__ v, const float* __restrict__ Wq,
             const float* __restrict__ Wk, const float* __restrict__ Wv,
             const float* __restrict__ Wo, f16* __restrict__ x16,
             f16* __restrict__ w16)
{
  const size_t NE4 = NE / 4, WE4 = WE / 4;
  size_t i = (size_t)blockIdx.x * 256 + threadIdx.x;
  const float* srcs[7] = {q, k, v, Wq, Wk, Wv, Wo};
  f16* dsts[7] = {x16, x16 + NE, x16 + 2 * NE,
                  w16, w16 + WE, w16 + 2 * WE, w16 + 3 * WE};
  const size_t sz4[7] = {NE4, NE4, NE4, WE4, WE4, WE4, WE4};
  int r = 0; size_t off = i;
  while (off >= sz4[r]) { off -= sz4[r]; ++r; }
  float4 f = reinterpret_cast<const float4*>(srcs[r])[off];
  half4 h; h[0] = (f16)f.x; h[1] = (f16)f.y; h[2] = (f16)f.z; h[3] = (f16)f.w;
  reinterpret_cast<half4*>(dsts[r])[off] = h;
}

// ---------------------------------------------------------------------------
// Fused QKV projection, f16-A, 128x128 tile (BK=64), XCD-grouped. (R5 frozen)
// ---------------------------------------------------------------------------
__global__ __launch_bounds__(256)
void qkv_gemm(const f16* __restrict__ x16, const f16* __restrict__ w16,
              const float* __restrict__ bq, const float* __restrict__ bk,
              const float* __restrict__ bv,
              f16* __restrict__ Qp, f16* __restrict__ Kp, f16* __restrict__ VpT)
{
  __shared__ f16 As[128][72];
  __shared__ f16 Bs[128][72];
  const int tid  = threadIdx.x;
  const int lane = tid & 63, wid = tid >> 6;
  const int lq   = lane & 15, quad = lane >> 4;
  const int wm   = (wid & 1) * 64, wn = (wid >> 1) * 64;

  // XCD-grouping decode (bijective over 576)
  const int d   = blockIdx.x;
  const int r8  = d & 7;
  const int j   = d >> 3;              // 0..71
  const int g   = r8 + 8 * (j / 6);    // group 0..95 = (widx, m-panel)
  const int nb  = j % 6;
  const int widx = g / 32;
  const int m0   = (g % 32) * 128;
  const int n0   = nb * 128;

  const f16* X = x16 + (size_t)widx * NE;
  const f16* W = w16 + (size_t)widx * WE;
  const float* Bv = (widx == 0) ? bq : (widx == 1) ? bk : bv;

  const int srow = tid >> 1, sseg = (tid & 1) * 32;
  const f16* aptr = X + (size_t)(m0 + srow) * DMODEL + sseg;
  const f16* bptr = W + (size_t)(n0 + srow) * DMODEL + sseg;

  half8 a4[4], b4[4];
#pragma unroll
  for (int u = 0; u < 4; ++u) {
    a4[u] = reinterpret_cast<const half8*>(aptr)[u];
    b4[u] = reinterpret_cast<const half8*>(bptr)[u];
  }

  f32x4 acc[4][4] = {};

  for (int k0 = 0; k0 < DMODEL; k0 += 64) {
#pragma unroll
    for (int u = 0; u < 4; ++u) {
      *reinterpret_cast<half8*>(&As[srow][sseg + u * 8]) = a4[u];
      *reinterpret_cast<half8*>(&Bs[srow][sseg + u * 8]) = b4[u];
    }
    __syncthreads();

    if (k0 + 64 < DMODEL) {
#pragma unroll
      for (int u = 0; u < 4; ++u) {
        a4[u] = reinterpret_cast<const half8*>(aptr + k0 + 64)[u];
        b4[u] = reinterpret_cast<const half8*>(bptr + k0 + 64)[u];
      }
    }

#pragma unroll
    for (int ks = 0; ks < 2; ++ks) {
      half8 bf[4];
#pragma unroll
      for (int nf = 0; nf < 4; ++nf)
        bf[nf] = *reinterpret_cast<half8*>(&Bs[wn + nf * 16 + lq][ks * 32 + quad * 8]);
#pragma unroll
      for (int mf = 0; mf < 4; ++mf) {
        half8 af = *reinterpret_cast<half8*>(&As[wm + mf * 16 + lq][ks * 32 + quad * 8]);
#pragma unroll
        for (int nf = 0; nf < 4; ++nf)
          acc[mf][nf] = MFMA16(af, bf[nf], acc[mf][nf]);
      }
    }
    __syncthreads();
  }

#pragma unroll
  for (int nf = 0; nf < 4; ++nf) {
    const int col  = n0 + wn + nf * 16 + lq;
    const float bias = Bv[col];
#pragma unroll
    for (int mf = 0; mf < 4; ++mf) {
      const int rowb = m0 + wm + mf * 16 + quad * 4;
      if (widx == 2) {
        half4 o4;
#pragma unroll
        for (int r = 0; r < 4; ++r) o4[r] = (f16)(acc[mf][nf][r] + bias);
        *reinterpret_cast<half4*>(VpT + (size_t)col * L_SEQ + rowb) = o4;
      } else if (widx == 0) {
#pragma unroll
        for (int r = 0; r < 4; ++r)
          Qp[(size_t)(rowb + r) * DMODEL + col] = (f16)((acc[mf][nf][r] + bias) * QSCALE);
      } else {
#pragma unroll
        for (int r = 0; r < 4; ++r)
          Kp[(size_t)(rowb + r) * DMODEL + col] = (f16)(acc[mf][nf][r] + bias);
      }
    }
  }
}

// ---------------------------------------------------------------------------
// Flash attention, ZERO-LDS main loop. K/V head-slices (512 KB each) are
// L2-resident (measured FETCH=15.4MB ~= compulsory, proving caches absorb the
// 768 MB of per-block re-reads) — so the LDS round-trip (8 ds_write + 8
// ds_read b128 + 1 barrier + 762K bank conflicts per dispatch) was pure
// overhead (Common-mistake #7). Fragments are now loaded straight from
// global in MFMA layout (per-lane 16B contiguous; wave = 32 rows x 32B),
// register-double-buffered one tile ahead. No barriers until the epilogue.
// ---------------------------------------------------------------------------
#define LOADK(dst, kt)                                                        \
  { _Pragma("unroll") for (int st = 0; st < 4; ++st)                          \
      dst[st] = *reinterpret_cast<const half8*>(                              \
          kptr + (size_t)(kt) * DMODEL + st * 16); }

#define LOADV(dst, kt)                                                        \
  { _Pragma("unroll") for (int a = 0; a < 2; ++a)                             \
    _Pragma("unroll") for (int st = 0; st < 2; ++st)                          \
      dst[2 * a + st] = *reinterpret_cast<const half8*>(                      \
          vptr + (size_t)a * 32 * L_SEQ + (kt) + st * 16); }

#define ATTN_STEP(kk, vv)                                                     \
  {                                                                           \
    __builtin_amdgcn_s_setprio(1);                                            \
    f32x16 s = {};                                                            \
    _Pragma("unroll")                                                         \
    for (int st = 0; st < 4; ++st) s = MFMA32(kk[st], qf[st], s);             \
    unsigned int pk[8];                                                       \
    _Pragma("unroll")                                                         \
    for (int i = 0; i < 8; ++i) {                                             \
      float p0 = __builtin_amdgcn_exp2f(s[2 * i]);                            \
      float p1 = __builtin_amdgcn_exp2f(s[2 * i + 1]);                        \
      lsum += p0 + p1;                                                        \
      pk[i] = pack2(p0, p1);                                                  \
    }                                                                         \
    _Pragma("unroll")                                                         \
    for (int st = 0; st < 2; ++st) {                                          \
      unsigned int w0 = pk[4 * st + 0], w1 = pk[4 * st + 1];                  \
      unsigned int w2 = pk[4 * st + 2], w3 = pk[4 * st + 3];                  \
      asm("v_permlane32_swap_b32 %0, %1" : "+v"(w0), "+v"(w2));               \
      asm("v_permlane32_swap_b32 %0, %1" : "+v"(w1), "+v"(w3));               \
      uint4v pw; pw[0] = w0; pw[1] = w1; pw[2] = w2; pw[3] = w3;              \
      half8 pf = __builtin_bit_cast(half8, pw);                               \
      _Pragma("unroll")                                                       \
      for (int a = 0; a < 2; ++a)                                             \
        oacc[a] = MFMA32(vv[2 * a + st], pf, oacc[a]);                        \
    }                                                                         \
    __builtin_amdgcn_s_setprio(0);                                            \
  }

__global__ __launch_bounds__(256, 3)
void attn_mfma4(const f16* __restrict__ Qp, const f16* __restrict__ Kp,
                const f16* __restrict__ VpT, f16* __restrict__ AO)
{
  const int h  = blockIdx.x;
  const int q0 = blockIdx.y * 64;
  const int tid  = threadIdx.x;
  const int lane = tid & 63, wid = tid >> 6;
  const int l31  = lane & 31, hc = lane >> 5;
  const int qh   = wid & 1, kh = wid >> 1;

  __shared__ __align__(16) char smem[25088];     // epilogue scratch only
  float* Of  = (float*)smem;                     // [2][64][32] f32 = 16384
  float* lf  = (float*)(smem + 16384);           // 64 f32
  f16*   Of16 = (f16*)(smem + 16640);            // [64][64] f16 = 8192

  // Q as B-operand frags (pre-scaled): n=q=l31, k=d=step*16+hc*8+j
  half8 qf[4];
#pragma unroll
  for (int st = 0; st < 4; ++st)
    qf[st] = *reinterpret_cast<const half8*>(
        Qp + (size_t)(q0 + qh * 32 + l31) * DMODEL + h * DKH + st * 16 + hc * 8);

  f32x16 oacc[2] = {};            // O^T: d-halves 32 x (32 q)
  float lsum = 0.0f;

  // per-lane fragment base pointers (global, MFMA layout)
  const f16* kptr = Kp  + (size_t)(kh * 32 + l31) * DMODEL + h * DKH + hc * 8;
  const f16* vptr = VpT + (size_t)(h * DKH + l31) * L_SEQ + kh * 32 + hc * 8;

  half8 ka[4], va[4], kb[4], vb[4];
  LOADK(ka, 0); LOADV(va, 0);

  for (int kt = 0; kt < L_SEQ; kt += 128) {
    LOADK(kb, kt + 64); LOADV(vb, kt + 64);      // prefetch odd tile
    ATTN_STEP(ka, va);
    if (kt + 128 < L_SEQ) {                      // prefetch next even tile
      LOADK(ka, kt + 128); LOADV(va, kt + 128);
    }
    ATTN_STEP(kb, vb);
  }

  // ---- combine key-halves via LDS (first LDS touch in the kernel)
  float lw = lsum + __shfl_xor(lsum, 32);   // wave-level l(q) for its key-half

  if (kh == 0) {
#pragma unroll
    for (int a = 0; a < 2; ++a)
#pragma unroll
      for (int r = 0; r < 16; ++r) {
        int d = a * 32 + (r & 3) + 8 * (r >> 2) + 4 * hc;
        Of[((qh * 64) + d) * 32 + l31] = oacc[a][r];
      }
    if (lane < 32) lf[qh * 32 + l31] = lw;
  }
  __syncthreads();
  if (kh == 1) {
    const float inv = 1.0f / (lf[qh * 32 + l31] + lw);
#pragma unroll
    for (int a = 0; a < 2; ++a)
#pragma unroll
      for (int r = 0; r < 16; ++r) {
        int d = a * 32 + (r & 3) + 8 * (r >> 2) + 4 * hc;
        float val = (Of[((qh * 64) + d) * 32 + l31] + oacc[a][r]) * inv;
        Of16[(qh * 32 + l31) * 64 + d] = (f16)val;
      }
  }
  __syncthreads();

  // ---- coalesced store: 64 q-rows x 64 d
  const int srow = tid >> 2, sseg = (tid & 3) * 16;
  *reinterpret_cast<half8*>(AO + (size_t)(q0 + srow) * DMODEL + h * DKH + sseg) =
      *reinterpret_cast<half8*>(&Of16[srow * 64 + sseg]);
  *reinterpret_cast<half8*>(AO + (size_t)(q0 + srow) * DMODEL + h * DKH + sseg + 8) =
      *reinterpret_cast<half8*>(&Of16[srow * 64 + sseg + 8]);
}

// ---------------------------------------------------------------------------
// Output projection, 128x128 tile (BK=64), XCD-grouped. (R5 frozen)
// ---------------------------------------------------------------------------
__global__ __launch_bounds__(256)
void out_gemm(const f16* __restrict__ A, const f16* __restrict__ W,
              const float* __restrict__ Bv, float* __restrict__ O)
{
  __shared__ f16 As[128][72];
  __shared__ f16 Bs[128][72];
  const int tid  = threadIdx.x;
  const int lane = tid & 63, wid = tid >> 6;
  const int lq   = lane & 15, quad = lane >> 4;
  const int wm   = (wid & 1) * 64, wn = (wid >> 1) * 64;

  // XCD-grouping decode (bijective over 192)
  const int d   = blockIdx.x;
  const int r8  = d & 7;
  const int j   = d >> 3;              // 0..23
  const int g   = r8 + 8 * (j / 6);    // m-panel 0..31
  const int nb  = j % 6;
  const int m0  = g * 128, n0 = nb * 128;

  const int srow = tid >> 1, sseg = (tid & 1) * 32;
  const f16* aptr = A + (size_t)(m0 + srow) * DMODEL + sseg;
  const f16* bptr = W + (size_t)(n0 + srow) * DMODEL + sseg;

  half8 a4[4], b4[4];
#pragma unroll
  for (int u = 0; u < 4; ++u) {
    a4[u] = reinterpret_cast<const half8*>(aptr)[u];
    b4[u] = reinterpret_cast<const half8*>(bptr)[u];
  }

  f32x4 acc[4][4] = {};

  for (int k0 = 0; k0 < DMODEL; k0 += 64) {
#pragma unroll
    for (int u = 0; u < 4; ++u) {
      *reinterpret_cast<half8*>(&As[srow][sseg + u * 8]) = a4[u];
      *reinterpret_cast<half8*>(&Bs[srow][sseg + u * 8]) = b4[u];
    }
    __syncthreads();

    if (k0 + 64 < DMODEL) {
#pragma unroll
      for (int u = 0; u < 4; ++u) {
        a4[u] = reinterpret_cast<const half8*>(aptr + k0 + 64)[u];
        b4[u] = reinterpret_cast<const half8*>(bptr + k0 + 64)[u];
      }
    }

#pragma unroll
    for (int ks = 0; ks < 2; ++ks) {
      half8 bf[4];
#pragma unroll
      for (int nf = 0; nf < 4; ++nf)
        bf[nf] = *reinterpret_cast<half8*>(&Bs[wn + nf * 16 + lq][ks * 32 + quad * 8]);
#pragma unroll
      for (int mf = 0; mf < 4; ++mf) {
        half8 af = *reinterpret_cast<half8*>(&As[wm + mf * 16 + lq][ks * 32 + quad * 8]);
#pragma unroll
        for (int nf = 0; nf < 4; ++nf)
          acc[mf][nf] = MFMA16(af, bf[nf], acc[mf][nf]);
      }
    }
    __syncthreads();
  }

#pragma unroll
  for (int nf = 0; nf < 4; ++nf) {
    const int col = n0 + wn + nf * 16 + lq;
    const float bias = Bv[col];
#pragma unroll
    for (int mf = 0; mf < 4; ++mf) {
      const int rowb = m0 + wm + mf * 16 + quad * 4;
#pragma unroll
      for (int r = 0; r < 4; ++r)
        O[(size_t)(rowb + r) * DMODEL + col] = acc[mf][nf][r] + bias;
    }
  }
}

// ---------------------------------------------------------------------------
extern "C" void kernel_launch(void* const* d_in, const int* in_sizes, int n_in,
                              void* d_out, int out_size, void* d_ws, size_t ws_size,
                              hipStream_t stream) {
  const float* q  = (const float*)d_in[0];
  const float* k  = (const float*)d_in[1];
  const float* v  = (const float*)d_in[2];
  const float* Wq = (const float*)d_in[3];
  const float* bq = (const float*)d_in[4];
  const float* Wk = (const float*)d_in[5];
  const float* bk = (const float*)d_in[6];
  const float* Wv = (const float*)d_in[7];
  const float* bv = (const float*)d_in[8];
  const float* Wo = (const float*)d_in[9];
  const float* bo = (const float*)d_in[10];
  float* out = (float*)d_out;

  f16* x16 = (f16*)d_ws;          // 3*NE
  f16* w16 = x16 + 3 * NE;        // 4*WE
  f16* Qp  = w16 + 4 * WE;        // NE, pre-scaled
  f16* Kp  = Qp + NE;             // NE
  f16* VpT = Kp + NE;             // NE (768, L)
  f16* AO  = VpT + NE;            // NE
  // total 48.8 MB

  const int ncvt = (int)((3 * (NE / 4) + 4 * (WE / 4)) / 256);
  cvt_all<<<ncvt, 256, 0, stream>>>(q, k, v, Wq, Wk, Wv, Wo, x16, w16);

  qkv_gemm<<<576, 256, 0, stream>>>(x16, w16, bq, bk, bv, Qp, Kp, VpT);

  dim3 gattn(NHEADS, L_SEQ / 64);
  attn_mfma4<<<gattn, 256, 0, stream>>>(Qp, Kp, VpT, AO);

  out_gemm<<<192, 256, 0, stream>>>(AO, w16 + 3 * WE, bo, out);
}

// Round 7
// 226.522 us; speedup vs baseline: 1.4285x; 1.4285x over previous
//
#include <hip/hip_runtime.h>
#include <stdint.h>
#include <math.h>

#define L_SEQ  4096
#define DMODEL 768
#define NHEADS 12
#define DKH    64
// 0.125 (=1/sqrt(64)) * log2(e): folded into Qp so p = exp2(S') needs no extra mul
#define QSCALE 0.18033688011112042f

typedef _Float16 f16;
typedef __attribute__((ext_vector_type(8))) _Float16 half8;
typedef __attribute__((ext_vector_type(4))) _Float16 half4;
typedef __attribute__((ext_vector_type(4))) float f32x4;
typedef __attribute__((ext_vector_type(16))) float f32x16;
typedef __attribute__((ext_vector_type(4))) unsigned int uint4v;

#define MFMA16(a, b, c) __builtin_amdgcn_mfma_f32_16x16x32_f16(a, b, c, 0, 0, 0)
#define MFMA32(a, b, c) __builtin_amdgcn_mfma_f32_32x32x16_f16(a, b, c, 0, 0, 0)

#define NE ((size_t)L_SEQ * DMODEL)      // 3,145,728
#define WE ((size_t)DMODEL * DMODEL)     // 589,824

static __device__ __forceinline__ unsigned int pack2(float a, float b) {
  return __builtin_bit_cast(unsigned int, __builtin_amdgcn_cvt_pkrtz(a, b));
}

// ---------------------------------------------------------------------------
// cvt_all: q,k,v (3*NE fp32) and Wq,Wk,Wv,Wo (4*WE fp32) -> f16. (frozen)
// ---------------------------------------------------------------------------
__global__ __launch_bounds__(256)
void cvt_all(const float* __restrict__ q, const float* __restrict__ k,
             const float* __restrict__ v, const float* __restrict__ Wq,
             const float* __restrict__ Wk, const float* __restrict__ Wv,
             const float* __restrict__ Wo, f16* __restrict__ x16,
             f16* __restrict__ w16)
{
  const size_t NE4 = NE / 4, WE4 = WE / 4;
  size_t i = (size_t)blockIdx.x * 256 + threadIdx.x;
  const float* srcs[7] = {q, k, v, Wq, Wk, Wv, Wo};
  f16* dsts[7] = {x16, x16 + NE, x16 + 2 * NE,
                  w16, w16 + WE, w16 + 2 * WE, w16 + 3 * WE};
  const size_t sz4[7] = {NE4, NE4, NE4, WE4, WE4, WE4, WE4};
  int r = 0; size_t off = i;
  while (off >= sz4[r]) { off -= sz4[r]; ++r; }
  float4 f = reinterpret_cast<const float4*>(srcs[r])[off];
  half4 h; h[0] = (f16)f.x; h[1] = (f16)f.y; h[2] = (f16)f.z; h[3] = (f16)f.w;
  reinterpret_cast<half4*>(dsts[r])[off] = h;
}

// ---------------------------------------------------------------------------
// Fused QKV projection, f16, 128x128 tile (BK=64), XCD-grouped, with
// 2-DEEP register prefetch: tile i+2's global load issues right after tile
// i's LDS write -> ~2 compute phases (~700-900 cyc) of latency slack.
// (R2 counters showed MfmaUtil 7 / VALUBusy 6: 86% latency-stall; 1-deep
// prefetch gave only ~300-400 cyc against 900-cyc HBM latency.)
// ---------------------------------------------------------------------------
#define GEMM_COMPUTE(acc)                                                     \
  { _Pragma("unroll")                                                         \
    for (int ks = 0; ks < 2; ++ks) {                                          \
      half8 bf[4];                                                            \
      _Pragma("unroll")                                                       \
      for (int nf = 0; nf < 4; ++nf)                                          \
        bf[nf] = *reinterpret_cast<half8*>(                                   \
            &Bs[wn + nf * 16 + lq][ks * 32 + quad * 8]);                      \
      _Pragma("unroll")                                                       \
      for (int mf = 0; mf < 4; ++mf) {                                        \
        half8 af = *reinterpret_cast<half8*>(                                 \
            &As[wm + mf * 16 + lq][ks * 32 + quad * 8]);                      \
        _Pragma("unroll")                                                     \
        for (int nf = 0; nf < 4; ++nf)                                        \
          acc[mf][nf] = MFMA16(af, bf[nf], acc[mf][nf]);                      \
      }                                                                       \
    } }

#define STAGE(aset, bset)                                                     \
  { _Pragma("unroll")                                                         \
    for (int u = 0; u < 4; ++u) {                                             \
      *reinterpret_cast<half8*>(&As[srow][sseg + u * 8]) = aset[u];           \
      *reinterpret_cast<half8*>(&Bs[srow][sseg + u * 8]) = bset[u];           \
    } }

#define GLOAD(aset, bset, t)                                                  \
  { _Pragma("unroll")                                                         \
    for (int u = 0; u < 4; ++u) {                                             \
      aset[u] = reinterpret_cast<const half8*>(aptr + (t) * 64)[u];           \
      bset[u] = reinterpret_cast<const half8*>(bptr + (t) * 64)[u];           \
    } }

__global__ __launch_bounds__(256)
void qkv_gemm(const f16* __restrict__ x16, const f16* __restrict__ w16,
              const float* __restrict__ bq, const float* __restrict__ bk,
              const float* __restrict__ bv,
              f16* __restrict__ Qp, f16* __restrict__ Kp, f16* __restrict__ VpT)
{
  __shared__ f16 As[128][72];
  __shared__ f16 Bs[128][72];
  const int tid  = threadIdx.x;
  const int lane = tid & 63, wid = tid >> 6;
  const int lq   = lane & 15, quad = lane >> 4;
  const int wm   = (wid & 1) * 64, wn = (wid >> 1) * 64;

  // XCD-grouping decode (bijective over 576)
  const int d   = blockIdx.x;
  const int r8  = d & 7;
  const int j   = d >> 3;              // 0..71
  const int g   = r8 + 8 * (j / 6);    // group 0..95 = (widx, m-panel)
  const int nb  = j % 6;
  const int widx = g / 32;
  const int m0   = (g % 32) * 128;
  const int n0   = nb * 128;

  const f16* X = x16 + (size_t)widx * NE;
  const f16* W = w16 + (size_t)widx * WE;
  const float* Bv = (widx == 0) ? bq : (widx == 1) ? bk : bv;

  const int srow = tid >> 1, sseg = (tid & 1) * 32;
  const f16* aptr = X + (size_t)(m0 + srow) * DMODEL + sseg;
  const f16* bptr = W + (size_t)(n0 + srow) * DMODEL + sseg;

  half8 aA[4], bA[4], aB[4], bB[4];
  GLOAD(aA, bA, 0);                    // tile 0
  GLOAD(aB, bB, 1);                    // tile 1

  f32x4 acc[4][4] = {};

  // DMODEL/64 = 12 tiles, unrolled x2 for static register-set selection
  for (int it = 0; it < 12; it += 2) {
    STAGE(aA, bA);
    __syncthreads();
    if (it + 2 < 12) GLOAD(aA, bA, it + 2);
    GEMM_COMPUTE(acc);
    __syncthreads();

    STAGE(aB, bB);
    __syncthreads();
    if (it + 3 < 12) GLOAD(aB, bB, it + 3);
    GEMM_COMPUTE(acc);
    __syncthreads();
  }

#pragma unroll
  for (int nf = 0; nf < 4; ++nf) {
    const int col  = n0 + wn + nf * 16 + lq;
    const float bias = Bv[col];
#pragma unroll
    for (int mf = 0; mf < 4; ++mf) {
      const int rowb = m0 + wm + mf * 16 + quad * 4;
      if (widx == 2) {
        half4 o4;
#pragma unroll
        for (int r = 0; r < 4; ++r) o4[r] = (f16)(acc[mf][nf][r] + bias);
        *reinterpret_cast<half4*>(VpT + (size_t)col * L_SEQ + rowb) = o4;
      } else if (widx == 0) {
#pragma unroll
        for (int r = 0; r < 4; ++r)
          Qp[(size_t)(rowb + r) * DMODEL + col] = (f16)((acc[mf][nf][r] + bias) * QSCALE);
      } else {
#pragma unroll
        for (int r = 0; r < 4; ++r)
          Kp[(size_t)(rowb + r) * DMODEL + col] = (f16)(acc[mf][nf][r] + bias);
      }
    }
  }
}

// ---------------------------------------------------------------------------
// Flash attention — R5 version VERBATIM (measured 72.9-74.5 us across three
// rounds). R6's zero-LDS variant proved LDS here is a latency cache: FETCH
// stayed compulsory (15.4 MB) but direct L2 fragment reads were latency-bound
// (11% MfmaUtil). Do not remove the staging.
// ---------------------------------------------------------------------------
__global__ __launch_bounds__(256, 3)
void attn_mfma4(const f16* __restrict__ Qp, const f16* __restrict__ Kp,
                const f16* __restrict__ VpT, f16* __restrict__ AO)
{
  const int h  = blockIdx.x;
  const int q0 = blockIdx.y * 64;
  const int tid  = threadIdx.x;
  const int lane = tid & 63, wid = tid >> 6;
  const int l31  = lane & 31, hc = lane >> 5;
  const int qh   = wid & 1, kh = wid >> 1;

  __shared__ __align__(16) char smem[36864];
  f16 (*Ks)[64][72] = (f16 (*)[64][72])smem;              // 2 x 9216 B (key,d)
  f16 (*Vt)[64][72] = (f16 (*)[64][72])(smem + 18432);    // 2 x 9216 B (d,key)
  float* Of  = (float*)smem;                      // epilogue: [2][64][32] f32 = 16384
  float* lf  = (float*)(smem + 16384);            // 64 f32
  f16*   Of16 = (f16*)(smem + 16640);             // [64][64] f16 = 8192

  // Q as B-operand frags (pre-scaled): n=q=l31, k=d=step*16+hc*8+j
  half8 qf[4];
#pragma unroll
  for (int st = 0; st < 4; ++st)
    qf[st] = *reinterpret_cast<const half8*>(
        Qp + (size_t)(q0 + qh * 32 + l31) * DMODEL + h * DKH + st * 16 + hc * 8);

  f32x16 oacc[2] = {};            // O^T: d-halves 32 x (32 q)
  float lsum = 0.0f;

  // staging: thread -> row tid>>2, 32 B at seg (tid&3)*16
  const int srow = tid >> 2, sseg = (tid & 3) * 16;
  const f16* kbase = Kp  + (size_t)srow * DMODEL + h * DKH + sseg;
  const f16* vbase = VpT + (size_t)(h * DKH + srow) * L_SEQ + sseg;

  half8 k0 = *reinterpret_cast<const half8*>(kbase);
  half8 k1 = *reinterpret_cast<const half8*>(kbase + 8);
  half8 v0 = *reinterpret_cast<const half8*>(vbase);
  half8 v1 = *reinterpret_cast<const half8*>(vbase + 8);

  int p = 0;
  for (int kt = 0; kt < L_SEQ; kt += 64) {
    *reinterpret_cast<half8*>(&Ks[p][srow][sseg])     = k0;
    *reinterpret_cast<half8*>(&Ks[p][srow][sseg + 8]) = k1;
    *reinterpret_cast<half8*>(&Vt[p][srow][sseg])     = v0;
    *reinterpret_cast<half8*>(&Vt[p][srow][sseg + 8]) = v1;
    __syncthreads();   // single barrier/iter: next iter writes the OTHER buffer

    if (kt + 64 < L_SEQ) {        // prefetch next K/V tile (overlaps compute)
      const f16* kn = kbase + (size_t)(kt + 64) * DMODEL;
      const f16* vn = vbase + (kt + 64);
      k0 = *reinterpret_cast<const half8*>(kn);
      k1 = *reinterpret_cast<const half8*>(kn + 8);
      v0 = *reinterpret_cast<const half8*>(vn);
      v1 = *reinterpret_cast<const half8*>(vn + 8);
    }

    __builtin_amdgcn_s_setprio(1);

    // ---- S^T = K·Q^T : 4 MFMAs (32key x 32q, k=d)
    f32x16 s = {};
#pragma unroll
    for (int st = 0; st < 4; ++st) {
      half8 kf = *reinterpret_cast<half8*>(&Ks[p][kh * 32 + l31][st * 16 + hc * 8]);
      s = MFMA32(kf, qf[st], s);
    }

    // ---- p = exp2(S'), per-lane l, pack pairs to b32
    unsigned int pk[8];
#pragma unroll
    for (int i = 0; i < 8; ++i) {
      float p0 = __builtin_amdgcn_exp2f(s[2 * i]);
      float p1 = __builtin_amdgcn_exp2f(s[2 * i + 1]);
      lsum += p0 + p1;
      pk[i] = pack2(p0, p1);
    }

    // ---- O^T += V^T·P^T : per k-step, 2 permlane32_swap produce all 4
    // B-operand words for both lane-halves; then 2 d-acc MFMAs.
#pragma unroll
    for (int st = 0; st < 2; ++st) {
      unsigned int w0 = pk[4 * st + 0], w1 = pk[4 * st + 1];
      unsigned int w2 = pk[4 * st + 2], w3 = pk[4 * st + 3];
      asm("v_permlane32_swap_b32 %0, %1" : "+v"(w0), "+v"(w2));
      asm("v_permlane32_swap_b32 %0, %1" : "+v"(w1), "+v"(w3));
      uint4v pw; pw[0] = w0; pw[1] = w1; pw[2] = w2; pw[3] = w3;
      half8 pf = __builtin_bit_cast(half8, pw);
#pragma unroll
      for (int a = 0; a < 2; ++a) {
        half8 vf = *reinterpret_cast<half8*>(&Vt[p][a * 32 + l31][kh * 32 + st * 16 + hc * 8]);
        oacc[a] = MFMA32(vf, pf, oacc[a]);
      }
    }
    __builtin_amdgcn_s_setprio(0);
    p ^= 1;
  }
  __syncthreads();   // protect epilogue LDS alias vs last tile's reads

  // ---- combine key-halves via LDS
  float lw = lsum + __shfl_xor(lsum, 32);   // wave-level l(q) for its key-half

  if (kh == 0) {
#pragma unroll
    for (int a = 0; a < 2; ++a)
#pragma unroll
      for (int r = 0; r < 16; ++r) {
        int d = a * 32 + (r & 3) + 8 * (r >> 2) + 4 * hc;
        Of[((qh * 64) + d) * 32 + l31] = oacc[a][r];
      }
    if (lane < 32) lf[qh * 32 + l31] = lw;
  }
  __syncthreads();
  if (kh == 1) {
    const float inv = 1.0f / (lf[qh * 32 + l31] + lw);
#pragma unroll
    for (int a = 0; a < 2; ++a)
#pragma unroll
      for (int r = 0; r < 16; ++r) {
        int d = a * 32 + (r & 3) + 8 * (r >> 2) + 4 * hc;
        float val = (Of[((qh * 64) + d) * 32 + l31] + oacc[a][r]) * inv;
        Of16[(qh * 32 + l31) * 64 + d] = (f16)val;
      }
  }
  __syncthreads();

  // ---- coalesced store: 64 q-rows x 64 d
  *reinterpret_cast<half8*>(AO + (size_t)(q0 + srow) * DMODEL + h * DKH + sseg) =
      *reinterpret_cast<half8*>(&Of16[srow * 64 + sseg]);
  *reinterpret_cast<half8*>(AO + (size_t)(q0 + srow) * DMODEL + h * DKH + sseg + 8) =
      *reinterpret_cast<half8*>(&Of16[srow * 64 + sseg + 8]);
}

// ---------------------------------------------------------------------------
// Output projection, 128x128 tile (BK=64), XCD-grouped, 2-deep register
// prefetch (same restructure as qkv_gemm).
// ---------------------------------------------------------------------------
__global__ __launch_bounds__(256)
void out_gemm(const f16* __restrict__ A, const f16* __restrict__ W,
              const float* __restrict__ Bv, float* __restrict__ O)
{
  __shared__ f16 As[128][72];
  __shared__ f16 Bs[128][72];
  const int tid  = threadIdx.x;
  const int lane = tid & 63, wid = tid >> 6;
  const int lq   = lane & 15, quad = lane >> 4;
  const int wm   = (wid & 1) * 64, wn = (wid >> 1) * 64;

  // XCD-grouping decode (bijective over 192)
  const int d   = blockIdx.x;
  const int r8  = d & 7;
  const int j   = d >> 3;              // 0..23
  const int g   = r8 + 8 * (j / 6);    // m-panel 0..31
  const int nb  = j % 6;
  const int m0  = g * 128, n0 = nb * 128;

  const int srow = tid >> 1, sseg = (tid & 1) * 32;
  const f16* aptr = A + (size_t)(m0 + srow) * DMODEL + sseg;
  const f16* bptr = W + (size_t)(n0 + srow) * DMODEL + sseg;

  half8 aA[4], bA[4], aB[4], bB[4];
  GLOAD(aA, bA, 0);
  GLOAD(aB, bB, 1);

  f32x4 acc[4][4] = {};

  for (int it = 0; it < 12; it += 2) {
    STAGE(aA, bA);
    __syncthreads();
    if (it + 2 < 12) GLOAD(aA, bA, it + 2);
    GEMM_COMPUTE(acc);
    __syncthreads();

    STAGE(aB, bB);
    __syncthreads();
    if (it + 3 < 12) GLOAD(aB, bB, it + 3);
    GEMM_COMPUTE(acc);
    __syncthreads();
  }

#pragma unroll
  for (int nf = 0; nf < 4; ++nf) {
    const int col = n0 + wn + nf * 16 + lq;
    const float bias = Bv[col];
#pragma unroll
    for (int mf = 0; mf < 4; ++mf) {
      const int rowb = m0 + wm + mf * 16 + quad * 4;
#pragma unroll
      for (int r = 0; r < 4; ++r)
        O[(size_t)(rowb + r) * DMODEL + col] = acc[mf][nf][r] + bias;
    }
  }
}

// ---------------------------------------------------------------------------
extern "C" void kernel_launch(void* const* d_in, const int* in_sizes, int n_in,
                              void* d_out, int out_size, void* d_ws, size_t ws_size,
                              hipStream_t stream) {
  const float* q  = (const float*)d_in[0];
  const float* k  = (const float*)d_in[1];
  const float* v  = (const float*)d_in[2];
  const float* Wq = (const float*)d_in[3];
  const float* bq = (const float*)d_in[4];
  const float* Wk = (const float*)d_in[5];
  const float* bk = (const float*)d_in[6];
  const float* Wv = (const float*)d_in[7];
  const float* bv = (const float*)d_in[8];
  const float* Wo = (const float*)d_in[9];
  const float* bo = (const float*)d_in[10];
  float* out = (float*)d_out;

  f16* x16 = (f16*)d_ws;          // 3*NE
  f16* w16 = x16 + 3 * NE;        // 4*WE
  f16* Qp  = w16 + 4 * WE;        // NE, pre-scaled
  f16* Kp  = Qp + NE;             // NE
  f16* VpT = Kp + NE;             // NE (768, L)
  f16* AO  = VpT + NE;            // NE
  // total 48.8 MB

  const int ncvt = (int)((3 * (NE / 4) + 4 * (WE / 4)) / 256);
  cvt_all<<<ncvt, 256, 0, stream>>>(q, k, v, Wq, Wk, Wv, Wo, x16, w16);

  qkv_gemm<<<576, 256, 0, stream>>>(x16, w16, bq, bk, bv, Qp, Kp, VpT);

  dim3 gattn(NHEADS, L_SEQ / 64);
  attn_mfma4<<<gattn, 256, 0, stream>>>(Qp, Kp, VpT, AO);

  out_gemm<<<192, 256, 0, stream>>>(AO, w16 + 3 * WE, bo, out);
}

// Round 8
// 220.510 us; speedup vs baseline: 1.4674x; 1.0273x over previous
//
#include <hip/hip_runtime.h>
#include <stdint.h>
#include <math.h>

#define L_SEQ  4096
#define DMODEL 768
#define NHEADS 12
#define DKH    64
// 0.125 (=1/sqrt(64)) * log2(e): folded into Qp so p = exp2(S') needs no extra mul
#define QSCALE 0.18033688011112042f

typedef _Float16 f16;
typedef __attribute__((ext_vector_type(8))) _Float16 half8;
typedef __attribute__((ext_vector_type(4))) _Float16 half4;
typedef __attribute__((ext_vector_type(4))) float f32x4;
typedef __attribute__((ext_vector_type(16))) float f32x16;
typedef __attribute__((ext_vector_type(4))) unsigned int uint4v;

#define MFMA16(a, b, c) __builtin_amdgcn_mfma_f32_16x16x32_f16(a, b, c, 0, 0, 0)
#define MFMA32(a, b, c) __builtin_amdgcn_mfma_f32_32x32x16_f16(a, b, c, 0, 0, 0)

#define NE ((size_t)L_SEQ * DMODEL)      // 3,145,728
#define WE ((size_t)DMODEL * DMODEL)     // 589,824

static __device__ __forceinline__ unsigned int pack2(float a, float b) {
  return __builtin_bit_cast(unsigned int, __builtin_amdgcn_cvt_pkrtz(a, b));
}

// ---------------------------------------------------------------------------
// cvt_all: q,k,v (3*NE fp32) and Wq,Wk,Wv,Wo (4*WE fp32) -> f16. (frozen)
// ---------------------------------------------------------------------------
__global__ __launch_bounds__(256)
void cvt_all(const float* __restrict__ q, const float* __restrict__ k,
             const float* __restrict__ v, const float* __restrict__ Wq,
             const float* __restrict__ Wk, const float* __restrict__ Wv,
             const float* __restrict__ Wo, f16* __restrict__ x16,
             f16* __restrict__ w16)
{
  const size_t NE4 = NE / 4, WE4 = WE / 4;
  size_t i = (size_t)blockIdx.x * 256 + threadIdx.x;
  const float* srcs[7] = {q, k, v, Wq, Wk, Wv, Wo};
  f16* dsts[7] = {x16, x16 + NE, x16 + 2 * NE,
                  w16, w16 + WE, w16 + 2 * WE, w16 + 3 * WE};
  const size_t sz4[7] = {NE4, NE4, NE4, WE4, WE4, WE4, WE4};
  int r = 0; size_t off = i;
  while (off >= sz4[r]) { off -= sz4[r]; ++r; }
  float4 f = reinterpret_cast<const float4*>(srcs[r])[off];
  half4 h; h[0] = (f16)f.x; h[1] = (f16)f.y; h[2] = (f16)f.z; h[3] = (f16)f.w;
  reinterpret_cast<half4*>(dsts[r])[off] = h;
}

// ---------------------------------------------------------------------------
// Fused QKV projection. BN back to 64: R7 showed the 2-deep prefetch was
// neutral and R2's 86%-idle at 2.25 blocks/CU was BARRIER-occupancy, not
// load latency (x16/w16 are L2/L3-resident post-cvt). 1152 blocks =
// 4.5 blocks/CU = 18 waves/CU. BK=64, 2-deep prefetch, XCD-grouped.
// ---------------------------------------------------------------------------
#define QSTAGE(aset, bset)                                                    \
  { _Pragma("unroll")                                                         \
    for (int u = 0; u < 4; ++u)                                               \
      *reinterpret_cast<half8*>(&As[arow][aseg + u * 8]) = aset[u];           \
    _Pragma("unroll")                                                         \
    for (int u = 0; u < 2; ++u)                                               \
      *reinterpret_cast<half8*>(&Bs[brow][bseg + u * 8]) = bset[u];           \
  }

#define QGLOAD(aset, bset, t)                                                 \
  { _Pragma("unroll")                                                         \
    for (int u = 0; u < 4; ++u)                                               \
      aset[u] = reinterpret_cast<const half8*>(aptr + (t) * 64)[u];           \
    _Pragma("unroll")                                                         \
    for (int u = 0; u < 2; ++u)                                               \
      bset[u] = reinterpret_cast<const half8*>(bptr + (t) * 64)[u];           \
  }

#define QCOMPUTE(acc)                                                         \
  { _Pragma("unroll")                                                         \
    for (int ks = 0; ks < 2; ++ks) {                                          \
      half8 bf[2];                                                            \
      _Pragma("unroll")                                                       \
      for (int nf = 0; nf < 2; ++nf)                                          \
        bf[nf] = *reinterpret_cast<half8*>(                                   \
            &Bs[wn + nf * 16 + lq][ks * 32 + quad * 8]);                      \
      _Pragma("unroll")                                                       \
      for (int mf = 0; mf < 4; ++mf) {                                        \
        half8 af = *reinterpret_cast<half8*>(                                 \
            &As[wm + mf * 16 + lq][ks * 32 + quad * 8]);                      \
        _Pragma("unroll")                                                     \
        for (int nf = 0; nf < 2; ++nf)                                        \
          acc[mf][nf] = MFMA16(af, bf[nf], acc[mf][nf]);                      \
      }                                                                       \
    } }

__global__ __launch_bounds__(256)
void qkv_gemm(const f16* __restrict__ x16, const f16* __restrict__ w16,
              const float* __restrict__ bq, const float* __restrict__ bk,
              const float* __restrict__ bv,
              f16* __restrict__ Qp, f16* __restrict__ Kp, f16* __restrict__ VpT)
{
  __shared__ f16 As[128][72];
  __shared__ f16 Bs[64][72];
  const int tid  = threadIdx.x;
  const int lane = tid & 63, wid = tid >> 6;
  const int lq   = lane & 15, quad = lane >> 4;
  const int wm   = (wid & 1) * 64, wn = (wid >> 1) * 32;

  // XCD-grouping decode (bijective over 1152): 96 groups x 12 n-blocks
  const int d   = blockIdx.x;
  const int r8  = d & 7;
  const int j   = d >> 3;              // 0..143
  const int g   = r8 + 8 * (j / 12);   // group 0..95 = (widx, m-panel)
  const int nb  = j % 12;
  const int widx = g / 32;
  const int m0   = (g % 32) * 128;
  const int n0   = nb * 64;

  const f16* X = x16 + (size_t)widx * NE;
  const f16* W = w16 + (size_t)widx * WE;
  const float* Bv = (widx == 0) ? bq : (widx == 1) ? bk : bv;

  const int arow = tid >> 1, aseg = (tid & 1) * 32;
  const int brow = tid >> 2, bseg = (tid & 3) * 16;
  const f16* aptr = X + (size_t)(m0 + arow) * DMODEL + aseg;
  const f16* bptr = W + (size_t)(n0 + brow) * DMODEL + bseg;

  half8 aA[4], bA[2], aB[4], bB[2];
  QGLOAD(aA, bA, 0);
  QGLOAD(aB, bB, 1);

  f32x4 acc[4][2] = {};

  for (int it = 0; it < 12; it += 2) {
    QSTAGE(aA, bA);
    __syncthreads();
    if (it + 2 < 12) QGLOAD(aA, bA, it + 2);
    QCOMPUTE(acc);
    __syncthreads();

    QSTAGE(aB, bB);
    __syncthreads();
    if (it + 3 < 12) QGLOAD(aB, bB, it + 3);
    QCOMPUTE(acc);
    __syncthreads();
  }

#pragma unroll
  for (int nf = 0; nf < 2; ++nf) {
    const int col  = n0 + wn + nf * 16 + lq;
    const float bias = Bv[col];
#pragma unroll
    for (int mf = 0; mf < 4; ++mf) {
      const int rowb = m0 + wm + mf * 16 + quad * 4;
      if (widx == 2) {
        half4 o4;
#pragma unroll
        for (int r = 0; r < 4; ++r) o4[r] = (f16)(acc[mf][nf][r] + bias);
        *reinterpret_cast<half4*>(VpT + (size_t)col * L_SEQ + rowb) = o4;
      } else if (widx == 0) {
#pragma unroll
        for (int r = 0; r < 4; ++r)
          Qp[(size_t)(rowb + r) * DMODEL + col] = (f16)((acc[mf][nf][r] + bias) * QSCALE);
      } else {
#pragma unroll
        for (int r = 0; r < 4; ++r)
          Kp[(size_t)(rowb + r) * DMODEL + col] = (f16)(acc[mf][nf][r] + bias);
      }
    }
  }
}

// ---------------------------------------------------------------------------
// Flash attention, 512-thread blocks, TWO 64-key tiles per iteration.
// 8 waves = (qh, kh, tt): wave handles q-half qh (32 q), key-half kh (32 of
// 64 keys) of tile tt. Grid still (12,64) = 768 blocks but now 2 blocks/CU
// x 8 waves = 16 waves/CU (was 12) and HALF the barrier rounds (32 iters).
// Inner loop per wave is byte-identical to the R5-proven code; only the
// epilogue becomes a 4-round partial combine over (kh,tt).
// ---------------------------------------------------------------------------
__global__ __launch_bounds__(512, 4)
void attn_mfma4(const f16* __restrict__ Qp, const f16* __restrict__ Kp,
                const f16* __restrict__ VpT, f16* __restrict__ AO)
{
  const int h  = blockIdx.x;
  const int q0 = blockIdx.y * 64;
  const int tid  = threadIdx.x;
  const int lane = tid & 63, wid = tid >> 6;
  const int l31  = lane & 31, hc = lane >> 5;
  const int qh   = wid & 1;
  const int kh   = (wid >> 1) & 1;
  const int tt   = wid >> 2;
  const int tb   = tt * 64;            // tile base within the 128-key buffer

  __shared__ __align__(16) char smem[71680];
  f16 (*Ks)[128][72]  = (f16 (*)[128][72])smem;            // 2 x 18432 B (key,d)
  f16 (*Vt)[64][136]  = (f16 (*)[64][136])(smem + 36864);  // 2 x 17408 B (d,key)
  float* Of  = (float*)smem;                      // epilogue: [2][64][32] f32 = 16384
  float* lf  = (float*)(smem + 16384);            // 64 f32
  f16*   Of16 = (f16*)(smem + 16640);             // [64][64] f16 = 8192

  // Q as B-operand frags (pre-scaled): n=q=l31, k=d=step*16+hc*8+j
  half8 qf[4];
#pragma unroll
  for (int st = 0; st < 4; ++st)
    qf[st] = *reinterpret_cast<const half8*>(
        Qp + (size_t)(q0 + qh * 32 + l31) * DMODEL + h * DKH + st * 16 + hc * 8);

  f32x16 oacc[2] = {};            // O^T: d-halves 32 x (32 q)
  float lsum = 0.0f;

  // staging (512 thr): K 128 rows x 64 d (32 B/thr), V^T 64 d x 128 cols (32 B/thr)
  const int krow = tid >> 2, kseg = (tid & 3) * 16;
  const int vrow = tid >> 3, vseg = (tid & 7) * 16;
  const f16* kbase = Kp  + (size_t)krow * DMODEL + h * DKH + kseg;
  const f16* vbase = VpT + (size_t)(h * DKH + vrow) * L_SEQ + vseg;

  half8 k0 = *reinterpret_cast<const half8*>(kbase);
  half8 k1 = *reinterpret_cast<const half8*>(kbase + 8);
  half8 v0 = *reinterpret_cast<const half8*>(vbase);
  half8 v1 = *reinterpret_cast<const half8*>(vbase + 8);

  int p = 0;
  for (int kt = 0; kt < L_SEQ; kt += 128) {
    *reinterpret_cast<half8*>(&Ks[p][krow][kseg])     = k0;
    *reinterpret_cast<half8*>(&Ks[p][krow][kseg + 8]) = k1;
    *reinterpret_cast<half8*>(&Vt[p][vrow][vseg])     = v0;
    *reinterpret_cast<half8*>(&Vt[p][vrow][vseg + 8]) = v1;
    __syncthreads();   // single barrier/iter: next iter writes the OTHER buffer

    if (kt + 128 < L_SEQ) {       // prefetch next 128-key pair
      const f16* kn = kbase + (size_t)(kt + 128) * DMODEL;
      const f16* vn = vbase + (kt + 128);
      k0 = *reinterpret_cast<const half8*>(kn);
      k1 = *reinterpret_cast<const half8*>(kn + 8);
      v0 = *reinterpret_cast<const half8*>(vn);
      v1 = *reinterpret_cast<const half8*>(vn + 8);
    }

    __builtin_amdgcn_s_setprio(1);

    // ---- S^T = K·Q^T : 4 MFMAs (32key x 32q, k=d)
    f32x16 s = {};
#pragma unroll
    for (int st = 0; st < 4; ++st) {
      half8 kf = *reinterpret_cast<half8*>(&Ks[p][tb + kh * 32 + l31][st * 16 + hc * 8]);
      s = MFMA32(kf, qf[st], s);
    }

    // ---- p = exp2(S'), per-lane l, pack pairs to b32
    unsigned int pk[8];
#pragma unroll
    for (int i = 0; i < 8; ++i) {
      float p0 = __builtin_amdgcn_exp2f(s[2 * i]);
      float p1 = __builtin_amdgcn_exp2f(s[2 * i + 1]);
      lsum += p0 + p1;
      pk[i] = pack2(p0, p1);
    }

    // ---- O^T += V^T·P^T : per k-step, 2 permlane32_swap produce all 4
    // B-operand words for both lane-halves; then 2 d-acc MFMAs.
#pragma unroll
    for (int st = 0; st < 2; ++st) {
      unsigned int w0 = pk[4 * st + 0], w1 = pk[4 * st + 1];
      unsigned int w2 = pk[4 * st + 2], w3 = pk[4 * st + 3];
      asm("v_permlane32_swap_b32 %0, %1" : "+v"(w0), "+v"(w2));
      asm("v_permlane32_swap_b32 %0, %1" : "+v"(w1), "+v"(w3));
      uint4v pw; pw[0] = w0; pw[1] = w1; pw[2] = w2; pw[3] = w3;
      half8 pf = __builtin_bit_cast(half8, pw);
#pragma unroll
      for (int a = 0; a < 2; ++a) {
        half8 vf = *reinterpret_cast<half8*>(
            &Vt[p][a * 32 + l31][tb + kh * 32 + st * 16 + hc * 8]);
        oacc[a] = MFMA32(vf, pf, oacc[a]);
      }
    }
    __builtin_amdgcn_s_setprio(0);
    p ^= 1;
  }
  __syncthreads();   // protect epilogue LDS alias vs last tile's reads

  // ---- combine the 4 partials (kh,tt) per q-half via LDS, 4 rounds
  const float lw = lsum + __shfl_xor(lsum, 32);   // per-q l for this wave's keys
  const int pid = kh + 2 * tt;

#pragma unroll
  for (int rnd = 0; rnd < 4; ++rnd) {
    if (pid == rnd) {
      if (rnd == 0) {
#pragma unroll
        for (int a = 0; a < 2; ++a)
#pragma unroll
          for (int r = 0; r < 16; ++r) {
            int dd = a * 32 + (r & 3) + 8 * (r >> 2) + 4 * hc;
            Of[((qh * 64) + dd) * 32 + l31] = oacc[a][r];
          }
        if (lane < 32) lf[qh * 32 + l31] = lw;
      } else if (rnd < 3) {
#pragma unroll
        for (int a = 0; a < 2; ++a)
#pragma unroll
          for (int r = 0; r < 16; ++r) {
            int dd = a * 32 + (r & 3) + 8 * (r >> 2) + 4 * hc;
            Of[((qh * 64) + dd) * 32 + l31] += oacc[a][r];
          }
        if (lane < 32) lf[qh * 32 + l31] += lw;
      } else {
        const float inv = 1.0f / (lf[qh * 32 + l31] + lw);
#pragma unroll
        for (int a = 0; a < 2; ++a)
#pragma unroll
          for (int r = 0; r < 16; ++r) {
            int dd = a * 32 + (r & 3) + 8 * (r >> 2) + 4 * hc;
            float val = (Of[((qh * 64) + dd) * 32 + l31] + oacc[a][r]) * inv;
            Of16[(qh * 32 + l31) * 64 + dd] = (f16)val;
          }
      }
    }
    __syncthreads();
  }

  // ---- coalesced store: 64 q-rows x 64 d (512 threads, one half8 each)
  const int orow = tid >> 3, oseg = (tid & 7) * 8;
  *reinterpret_cast<half8*>(AO + (size_t)(q0 + orow) * DMODEL + h * DKH + oseg) =
      *reinterpret_cast<half8*>(&Of16[orow * 64 + oseg]);
}

// ---------------------------------------------------------------------------
// Output projection, 128x128 tile (BK=64), XCD-grouped, 2-deep register
// prefetch. (R7 frozen)
// ---------------------------------------------------------------------------
#define GEMM_COMPUTE(acc)                                                     \
  { _Pragma("unroll")                                                         \
    for (int ks = 0; ks < 2; ++ks) {                                          \
      half8 bf[4];                                                            \
      _Pragma("unroll")                                                       \
      for (int nf = 0; nf < 4; ++nf)                                          \
        bf[nf] = *reinterpret_cast<half8*>(                                   \
            &Bs[wn + nf * 16 + lq][ks * 32 + quad * 8]);                      \
      _Pragma("unroll")                                                       \
      for (int mf = 0; mf < 4; ++mf) {                                        \
        half8 af = *reinterpret_cast<half8*>(                                 \
            &As[wm + mf * 16 + lq][ks * 32 + quad * 8]);                      \
        _Pragma("unroll")                                                     \
        for (int nf = 0; nf < 4; ++nf)                                        \
          acc[mf][nf] = MFMA16(af, bf[nf], acc[mf][nf]);                      \
      }                                                                       \
    } }

#define STAGE(aset, bset)                                                     \
  { _Pragma("unroll")                                                         \
    for (int u = 0; u < 4; ++u) {                                             \
      *reinterpret_cast<half8*>(&As[srow][sseg + u * 8]) = aset[u];           \
      *reinterpret_cast<half8*>(&Bs[srow][sseg + u * 8]) = bset[u];           \
    } }

#define GLOAD(aset, bset, t)                                                  \
  { _Pragma("unroll")                                                         \
    for (int u = 0; u < 4; ++u) {                                             \
      aset[u] = reinterpret_cast<const half8*>(aptr + (t) * 64)[u];           \
      bset[u] = reinterpret_cast<const half8*>(bptr + (t) * 64)[u];           \
    } }

__global__ __launch_bounds__(256)
void out_gemm(const f16* __restrict__ A, const f16* __restrict__ W,
              const float* __restrict__ Bv, float* __restrict__ O)
{
  __shared__ f16 As[128][72];
  __shared__ f16 Bs[128][72];
  const int tid  = threadIdx.x;
  const int lane = tid & 63, wid = tid >> 6;
  const int lq   = lane & 15, quad = lane >> 4;
  const int wm   = (wid & 1) * 64, wn = (wid >> 1) * 64;

  // XCD-grouping decode (bijective over 192)
  const int d   = blockIdx.x;
  const int r8  = d & 7;
  const int j   = d >> 3;              // 0..23
  const int g   = r8 + 8 * (j / 6);    // m-panel 0..31
  const int nb  = j % 6;
  const int m0  = g * 128, n0 = nb * 128;

  const int srow = tid >> 1, sseg = (tid & 1) * 32;
  const f16* aptr = A + (size_t)(m0 + srow) * DMODEL + sseg;
  const f16* bptr = W + (size_t)(n0 + srow) * DMODEL + sseg;

  half8 aA[4], bA[4], aB[4], bB[4];
  GLOAD(aA, bA, 0);
  GLOAD(aB, bB, 1);

  f32x4 acc[4][4] = {};

  for (int it = 0; it < 12; it += 2) {
    STAGE(aA, bA);
    __syncthreads();
    if (it + 2 < 12) GLOAD(aA, bA, it + 2);
    GEMM_COMPUTE(acc);
    __syncthreads();

    STAGE(aB, bB);
    __syncthreads();
    if (it + 3 < 12) GLOAD(aB, bB, it + 3);
    GEMM_COMPUTE(acc);
    __syncthreads();
  }

#pragma unroll
  for (int nf = 0; nf < 4; ++nf) {
    const int col = n0 + wn + nf * 16 + lq;
    const float bias = Bv[col];
#pragma unroll
    for (int mf = 0; mf < 4; ++mf) {
      const int rowb = m0 + wm + mf * 16 + quad * 4;
#pragma unroll
      for (int r = 0; r < 4; ++r)
        O[(size_t)(rowb + r) * DMODEL + col] = acc[mf][nf][r] + bias;
    }
  }
}

// ---------------------------------------------------------------------------
extern "C" void kernel_launch(void* const* d_in, const int* in_sizes, int n_in,
                              void* d_out, int out_size, void* d_ws, size_t ws_size,
                              hipStream_t stream) {
  const float* q  = (const float*)d_in[0];
  const float* k  = (const float*)d_in[1];
  const float* v  = (const float*)d_in[2];
  const float* Wq = (const float*)d_in[3];
  const float* bq = (const float*)d_in[4];
  const float* Wk = (const float*)d_in[5];
  const float* bk = (const float*)d_in[6];
  const float* Wv = (const float*)d_in[7];
  const float* bv = (const float*)d_in[8];
  const float* Wo = (const float*)d_in[9];
  const float* bo = (const float*)d_in[10];
  float* out = (float*)d_out;

  f16* x16 = (f16*)d_ws;          // 3*NE
  f16* w16 = x16 + 3 * NE;        // 4*WE
  f16* Qp  = w16 + 4 * WE;        // NE, pre-scaled
  f16* Kp  = Qp + NE;             // NE
  f16* VpT = Kp + NE;             // NE (768, L)
  f16* AO  = VpT + NE;            // NE
  // total 48.8 MB

  const int ncvt = (int)((3 * (NE / 4) + 4 * (WE / 4)) / 256);
  cvt_all<<<ncvt, 256, 0, stream>>>(q, k, v, Wq, Wk, Wv, Wo, x16, w16);

  qkv_gemm<<<1152, 256, 0, stream>>>(x16, w16, bq, bk, bv, Qp, Kp, VpT);

  dim3 gattn(NHEADS, L_SEQ / 64);
  attn_mfma4<<<gattn, 512, 0, stream>>>(Qp, Kp, VpT, AO);

  out_gemm<<<192, 256, 0, stream>>>(AO, w16 + 3 * WE, bo, out);
}

// Round 9
// 214.085 us; speedup vs baseline: 1.5114x; 1.0300x over previous
//
#include <hip/hip_runtime.h>
#include <stdint.h>
#include <math.h>

#define L_SEQ  4096
#define DMODEL 768
#define NHEADS 12
#define DKH    64
// 0.125 (=1/sqrt(64)) * log2(e): folded into Qp so p = exp2(S') needs no extra mul
#define QSCALE 0.18033688011112042f

typedef _Float16 f16;
typedef __attribute__((ext_vector_type(8))) _Float16 half8;
typedef __attribute__((ext_vector_type(4))) _Float16 half4;
typedef __attribute__((ext_vector_type(4))) float f32x4;
typedef __attribute__((ext_vector_type(16))) float f32x16;
typedef __attribute__((ext_vector_type(4))) unsigned int uint4v;

#define MFMA16(a, b, c) __builtin_amdgcn_mfma_f32_16x16x32_f16(a, b, c, 0, 0, 0)
#define MFMA32(a, b, c) __builtin_amdgcn_mfma_f32_32x32x16_f16(a, b, c, 0, 0, 0)

#define NE ((size_t)L_SEQ * DMODEL)      // 3,145,728
#define WE ((size_t)DMODEL * DMODEL)     // 589,824

static __device__ __forceinline__ unsigned int pack2(float a, float b) {
  return __builtin_bit_cast(unsigned int, __builtin_amdgcn_cvt_pkrtz(a, b));
}

// ---------------------------------------------------------------------------
// cvt_all: q,k,v (3*NE fp32) and Wq,Wk,Wv,Wo (4*WE fp32) -> f16. (frozen)
// ---------------------------------------------------------------------------
__global__ __launch_bounds__(256)
void cvt_all(const float* __restrict__ q, const float* __restrict__ k,
             const float* __restrict__ v, const float* __restrict__ Wq,
             const float* __restrict__ Wk, const float* __restrict__ Wv,
             const float* __restrict__ Wo, f16* __restrict__ x16,
             f16* __restrict__ w16)
{
  const size_t NE4 = NE / 4, WE4 = WE / 4;
  size_t i = (size_t)blockIdx.x * 256 + threadIdx.x;
  const float* srcs[7] = {q, k, v, Wq, Wk, Wv, Wo};
  f16* dsts[7] = {x16, x16 + NE, x16 + 2 * NE,
                  w16, w16 + WE, w16 + 2 * WE, w16 + 3 * WE};
  const size_t sz4[7] = {NE4, NE4, NE4, WE4, WE4, WE4, WE4};
  int r = 0; size_t off = i;
  while (off >= sz4[r]) { off -= sz4[r]; ++r; }
  float4 f = reinterpret_cast<const float4*>(srcs[r])[off];
  half4 h; h[0] = (f16)f.x; h[1] = (f16)f.y; h[2] = (f16)f.z; h[3] = (f16)f.w;
  reinterpret_cast<half4*>(dsts[r])[off] = h;
}

// ---------------------------------------------------------------------------
// Fused QKV projection — R8 version VERBATIM (best measured: non-attn 143.9).
// BN=64, BK=64, 2-deep prefetch, XCD-grouped, 1152 blocks = 18 waves/CU.
// ---------------------------------------------------------------------------
#define QSTAGE(aset, bset)                                                    \
  { _Pragma("unroll")                                                         \
    for (int u = 0; u < 4; ++u)                                               \
      *reinterpret_cast<half8*>(&As[arow][aseg + u * 8]) = aset[u];           \
    _Pragma("unroll")                                                         \
    for (int u = 0; u < 2; ++u)                                               \
      *reinterpret_cast<half8*>(&Bs[brow][bseg + u * 8]) = bset[u];           \
  }

#define QGLOAD(aset, bset, t)                                                 \
  { _Pragma("unroll")                                                         \
    for (int u = 0; u < 4; ++u)                                               \
      aset[u] = reinterpret_cast<const half8*>(aptr + (t) * 64)[u];           \
    _Pragma("unroll")                                                         \
    for (int u = 0; u < 2; ++u)                                               \
      bset[u] = reinterpret_cast<const half8*>(bptr + (t) * 64)[u];           \
  }

#define QCOMPUTE(acc)                                                         \
  { _Pragma("unroll")                                                         \
    for (int ks = 0; ks < 2; ++ks) {                                          \
      half8 bf[2];                                                            \
      _Pragma("unroll")                                                       \
      for (int nf = 0; nf < 2; ++nf)                                          \
        bf[nf] = *reinterpret_cast<half8*>(                                   \
            &Bs[wn + nf * 16 + lq][ks * 32 + quad * 8]);                      \
      _Pragma("unroll")                                                       \
      for (int mf = 0; mf < 4; ++mf) {                                        \
        half8 af = *reinterpret_cast<half8*>(                                 \
            &As[wm + mf * 16 + lq][ks * 32 + quad * 8]);                      \
        _Pragma("unroll")                                                     \
        for (int nf = 0; nf < 2; ++nf)                                        \
          acc[mf][nf] = MFMA16(af, bf[nf], acc[mf][nf]);                      \
      }                                                                       \
    } }

__global__ __launch_bounds__(256)
void qkv_gemm(const f16* __restrict__ x16, const f16* __restrict__ w16,
              const float* __restrict__ bq, const float* __restrict__ bk,
              const float* __restrict__ bv,
              f16* __restrict__ Qp, f16* __restrict__ Kp, f16* __restrict__ VpT)
{
  __shared__ f16 As[128][72];
  __shared__ f16 Bs[64][72];
  const int tid  = threadIdx.x;
  const int lane = tid & 63, wid = tid >> 6;
  const int lq   = lane & 15, quad = lane >> 4;
  const int wm   = (wid & 1) * 64, wn = (wid >> 1) * 32;

  // XCD-grouping decode (bijective over 1152): 96 groups x 12 n-blocks
  const int d   = blockIdx.x;
  const int r8  = d & 7;
  const int j   = d >> 3;              // 0..143
  const int g   = r8 + 8 * (j / 12);   // group 0..95 = (widx, m-panel)
  const int nb  = j % 12;
  const int widx = g / 32;
  const int m0   = (g % 32) * 128;
  const int n0   = nb * 64;

  const f16* X = x16 + (size_t)widx * NE;
  const f16* W = w16 + (size_t)widx * WE;
  const float* Bv = (widx == 0) ? bq : (widx == 1) ? bk : bv;

  const int arow = tid >> 1, aseg = (tid & 1) * 32;
  const int brow = tid >> 2, bseg = (tid & 3) * 16;
  const f16* aptr = X + (size_t)(m0 + arow) * DMODEL + aseg;
  const f16* bptr = W + (size_t)(n0 + brow) * DMODEL + bseg;

  half8 aA[4], bA[2], aB[4], bB[2];
  QGLOAD(aA, bA, 0);
  QGLOAD(aB, bB, 1);

  f32x4 acc[4][2] = {};

  for (int it = 0; it < 12; it += 2) {
    QSTAGE(aA, bA);
    __syncthreads();
    if (it + 2 < 12) QGLOAD(aA, bA, it + 2);
    QCOMPUTE(acc);
    __syncthreads();

    QSTAGE(aB, bB);
    __syncthreads();
    if (it + 3 < 12) QGLOAD(aB, bB, it + 3);
    QCOMPUTE(acc);
    __syncthreads();
  }

#pragma unroll
  for (int nf = 0; nf < 2; ++nf) {
    const int col  = n0 + wn + nf * 16 + lq;
    const float bias = Bv[col];
#pragma unroll
    for (int mf = 0; mf < 4; ++mf) {
      const int rowb = m0 + wm + mf * 16 + quad * 4;
      if (widx == 2) {
        half4 o4;
#pragma unroll
        for (int r = 0; r < 4; ++r) o4[r] = (f16)(acc[mf][nf][r] + bias);
        *reinterpret_cast<half4*>(VpT + (size_t)col * L_SEQ + rowb) = o4;
      } else if (widx == 0) {
#pragma unroll
        for (int r = 0; r < 4; ++r)
          Qp[(size_t)(rowb + r) * DMODEL + col] = (f16)((acc[mf][nf][r] + bias) * QSCALE);
      } else {
#pragma unroll
        for (int r = 0; r < 4; ++r)
          Kp[(size_t)(rowb + r) * DMODEL + col] = (f16)(acc[mf][nf][r] + bias);
      }
    }
  }
}

// ---------------------------------------------------------------------------
// Flash attention — R5 version VERBATIM (256 thr, 3 blocks/CU; measured
// 72.9-74.5 us across rounds 1/3/4/5/7). R8's 512-thread variant regressed
// (76.6 us: 5x bank conflicts from the [64][136] V^T layout outweighed the
// +33% occupancy). This structure is the measured optimum.
// ---------------------------------------------------------------------------
__global__ __launch_bounds__(256, 3)
void attn_mfma4(const f16* __restrict__ Qp, const f16* __restrict__ Kp,
                const f16* __restrict__ VpT, f16* __restrict__ AO)
{
  const int h  = blockIdx.x;
  const int q0 = blockIdx.y * 64;
  const int tid  = threadIdx.x;
  const int lane = tid & 63, wid = tid >> 6;
  const int l31  = lane & 31, hc = lane >> 5;
  const int qh   = wid & 1, kh = wid >> 1;

  __shared__ __align__(16) char smem[36864];
  f16 (*Ks)[64][72] = (f16 (*)[64][72])smem;              // 2 x 9216 B (key,d)
  f16 (*Vt)[64][72] = (f16 (*)[64][72])(smem + 18432);    // 2 x 9216 B (d,key)
  float* Of  = (float*)smem;                      // epilogue: [2][64][32] f32 = 16384
  float* lf  = (float*)(smem + 16384);            // 64 f32
  f16*   Of16 = (f16*)(smem + 16640);             // [64][64] f16 = 8192

  // Q as B-operand frags (pre-scaled): n=q=l31, k=d=step*16+hc*8+j
  half8 qf[4];
#pragma unroll
  for (int st = 0; st < 4; ++st)
    qf[st] = *reinterpret_cast<const half8*>(
        Qp + (size_t)(q0 + qh * 32 + l31) * DMODEL + h * DKH + st * 16 + hc * 8);

  f32x16 oacc[2] = {};            // O^T: d-halves 32 x (32 q)
  float lsum = 0.0f;

  // staging: thread -> row tid>>2, 32 B at seg (tid&3)*16
  const int srow = tid >> 2, sseg = (tid & 3) * 16;
  const f16* kbase = Kp  + (size_t)srow * DMODEL + h * DKH + sseg;
  const f16* vbase = VpT + (size_t)(h * DKH + srow) * L_SEQ + sseg;

  half8 k0 = *reinterpret_cast<const half8*>(kbase);
  half8 k1 = *reinterpret_cast<const half8*>(kbase + 8);
  half8 v0 = *reinterpret_cast<const half8*>(vbase);
  half8 v1 = *reinterpret_cast<const half8*>(vbase + 8);

  int p = 0;
  for (int kt = 0; kt < L_SEQ; kt += 64) {
    *reinterpret_cast<half8*>(&Ks[p][srow][sseg])     = k0;
    *reinterpret_cast<half8*>(&Ks[p][srow][sseg + 8]) = k1;
    *reinterpret_cast<half8*>(&Vt[p][srow][sseg])     = v0;
    *reinterpret_cast<half8*>(&Vt[p][srow][sseg + 8]) = v1;
    __syncthreads();   // single barrier/iter: next iter writes the OTHER buffer

    if (kt + 64 < L_SEQ) {        // prefetch next K/V tile (overlaps compute)
      const f16* kn = kbase + (size_t)(kt + 64) * DMODEL;
      const f16* vn = vbase + (kt + 64);
      k0 = *reinterpret_cast<const half8*>(kn);
      k1 = *reinterpret_cast<const half8*>(kn + 8);
      v0 = *reinterpret_cast<const half8*>(vn);
      v1 = *reinterpret_cast<const half8*>(vn + 8);
    }

    __builtin_amdgcn_s_setprio(1);

    // ---- S^T = K·Q^T : 4 MFMAs (32key x 32q, k=d)
    f32x16 s = {};
#pragma unroll
    for (int st = 0; st < 4; ++st) {
      half8 kf = *reinterpret_cast<half8*>(&Ks[p][kh * 32 + l31][st * 16 + hc * 8]);
      s = MFMA32(kf, qf[st], s);
    }

    // ---- p = exp2(S'), per-lane l, pack pairs to b32
    unsigned int pk[8];
#pragma unroll
    for (int i = 0; i < 8; ++i) {
      float p0 = __builtin_amdgcn_exp2f(s[2 * i]);
      float p1 = __builtin_amdgcn_exp2f(s[2 * i + 1]);
      lsum += p0 + p1;
      pk[i] = pack2(p0, p1);
    }

    // ---- O^T += V^T·P^T : per k-step, 2 permlane32_swap produce all 4
    // B-operand words for both lane-halves; then 2 d-acc MFMAs.
#pragma unroll
    for (int st = 0; st < 2; ++st) {
      unsigned int w0 = pk[4 * st + 0], w1 = pk[4 * st + 1];
      unsigned int w2 = pk[4 * st + 2], w3 = pk[4 * st + 3];
      asm("v_permlane32_swap_b32 %0, %1" : "+v"(w0), "+v"(w2));
      asm("v_permlane32_swap_b32 %0, %1" : "+v"(w1), "+v"(w3));
      uint4v pw; pw[0] = w0; pw[1] = w1; pw[2] = w2; pw[3] = w3;
      half8 pf = __builtin_bit_cast(half8, pw);
#pragma unroll
      for (int a = 0; a < 2; ++a) {
        half8 vf = *reinterpret_cast<half8*>(&Vt[p][a * 32 + l31][kh * 32 + st * 16 + hc * 8]);
        oacc[a] = MFMA32(vf, pf, oacc[a]);
      }
    }
    __builtin_amdgcn_s_setprio(0);
    p ^= 1;
  }
  __syncthreads();   // protect epilogue LDS alias vs last tile's reads

  // ---- combine key-halves via LDS
  float lw = lsum + __shfl_xor(lsum, 32);   // wave-level l(q) for its key-half

  if (kh == 0) {
#pragma unroll
    for (int a = 0; a < 2; ++a)
#pragma unroll
      for (int r = 0; r < 16; ++r) {
        int d = a * 32 + (r & 3) + 8 * (r >> 2) + 4 * hc;
        Of[((qh * 64) + d) * 32 + l31] = oacc[a][r];
      }
    if (lane < 32) lf[qh * 32 + l31] = lw;
  }
  __syncthreads();
  if (kh == 1) {
    const float inv = 1.0f / (lf[qh * 32 + l31] + lw);
#pragma unroll
    for (int a = 0; a < 2; ++a)
#pragma unroll
      for (int r = 0; r < 16; ++r) {
        int d = a * 32 + (r & 3) + 8 * (r >> 2) + 4 * hc;
        float val = (Of[((qh * 64) + d) * 32 + l31] + oacc[a][r]) * inv;
        Of16[(qh * 32 + l31) * 64 + d] = (f16)val;
      }
  }
  __syncthreads();

  // ---- coalesced store: 64 q-rows x 64 d
  *reinterpret_cast<half8*>(AO + (size_t)(q0 + srow) * DMODEL + h * DKH + sseg) =
      *reinterpret_cast<half8*>(&Of16[srow * 64 + sseg]);
  *reinterpret_cast<half8*>(AO + (size_t)(q0 + srow) * DMODEL + h * DKH + sseg + 8) =
      *reinterpret_cast<half8*>(&Of16[srow * 64 + sseg + 8]);
}

// ---------------------------------------------------------------------------
// Output projection — R8 version VERBATIM. 128x128 tile (BK=64), XCD-grouped,
// 2-deep register prefetch.
// ---------------------------------------------------------------------------
#define GEMM_COMPUTE(acc)                                                     \
  { _Pragma("unroll")                                                         \
    for (int ks = 0; ks < 2; ++ks) {                                          \
      half8 bf[4];                                                            \
      _Pragma("unroll")                                                       \
      for (int nf = 0; nf < 4; ++nf)                                          \
        bf[nf] = *reinterpret_cast<half8*>(                                   \
            &Bs[wn + nf * 16 + lq][ks * 32 + quad * 8]);                      \
      _Pragma("unroll")                                                       \
      for (int mf = 0; mf < 4; ++mf) {                                        \
        half8 af = *reinterpret_cast<half8*>(                                 \
            &As[wm + mf * 16 + lq][ks * 32 + quad * 8]);                      \
        _Pragma("unroll")                                                     \
        for (int nf = 0; nf < 4; ++nf)                                        \
          acc[mf][nf] = MFMA16(af, bf[nf], acc[mf][nf]);                      \
      }                                                                       \
    } }

#define STAGE(aset, bset)                                                     \
  { _Pragma("unroll")                                                         \
    for (int u = 0; u < 4; ++u) {                                             \
      *reinterpret_cast<half8*>(&As[srow][sseg + u * 8]) = aset[u];           \
      *reinterpret_cast<half8*>(&Bs[srow][sseg + u * 8]) = bset[u];           \
    } }

#define GLOAD(aset, bset, t)                                                  \
  { _Pragma("unroll")                                                         \
    for (int u = 0; u < 4; ++u) {                                             \
      aset[u] = reinterpret_cast<const half8*>(aptr + (t) * 64)[u];           \
      bset[u] = reinterpret_cast<const half8*>(bptr + (t) * 64)[u];           \
    } }

__global__ __launch_bounds__(256)
void out_gemm(const f16* __restrict__ A, const f16* __restrict__ W,
              const float* __restrict__ Bv, float* __restrict__ O)
{
  __shared__ f16 As[128][72];
  __shared__ f16 Bs[128][72];
  const int tid  = threadIdx.x;
  const int lane = tid & 63, wid = tid >> 6;
  const int lq   = lane & 15, quad = lane >> 4;
  const int wm   = (wid & 1) * 64, wn = (wid >> 1) * 64;

  // XCD-grouping decode (bijective over 192)
  const int d   = blockIdx.x;
  const int r8  = d & 7;
  const int j   = d >> 3;              // 0..23
  const int g   = r8 + 8 * (j / 6);    // m-panel 0..31
  const int nb  = j % 6;
  const int m0  = g * 128, n0 = nb * 128;

  const int srow = tid >> 1, sseg = (tid & 1) * 32;
  const f16* aptr = A + (size_t)(m0 + srow) * DMODEL + sseg;
  const f16* bptr = W + (size_t)(n0 + srow) * DMODEL + sseg;

  half8 aA[4], bA[4], aB[4], bB[4];
  GLOAD(aA, bA, 0);
  GLOAD(aB, bB, 1);

  f32x4 acc[4][4] = {};

  for (int it = 0; it < 12; it += 2) {
    STAGE(aA, bA);
    __syncthreads();
    if (it + 2 < 12) GLOAD(aA, bA, it + 2);
    GEMM_COMPUTE(acc);
    __syncthreads();

    STAGE(aB, bB);
    __syncthreads();
    if (it + 3 < 12) GLOAD(aB, bB, it + 3);
    GEMM_COMPUTE(acc);
    __syncthreads();
  }

#pragma unroll
  for (int nf = 0; nf < 4; ++nf) {
    const int col = n0 + wn + nf * 16 + lq;
    const float bias = Bv[col];
#pragma unroll
    for (int mf = 0; mf < 4; ++mf) {
      const int rowb = m0 + wm + mf * 16 + quad * 4;
#pragma unroll
      for (int r = 0; r < 4; ++r)
        O[(size_t)(rowb + r) * DMODEL + col] = acc[mf][nf][r] + bias;
    }
  }
}

// ---------------------------------------------------------------------------
extern "C" void kernel_launch(void* const* d_in, const int* in_sizes, int n_in,
                              void* d_out, int out_size, void* d_ws, size_t ws_size,
                              hipStream_t stream) {
  const float* q  = (const float*)d_in[0];
  const float* k  = (const float*)d_in[1];
  const float* v  = (const float*)d_in[2];
  const float* Wq = (const float*)d_in[3];
  const float* bq = (const float*)d_in[4];
  const float* Wk = (const float*)d_in[5];
  const float* bk = (const float*)d_in[6];
  const float* Wv = (const float*)d_in[7];
  const float* bv = (const float*)d_in[8];
  const float* Wo = (const float*)d_in[9];
  const float* bo = (const float*)d_in[10];
  float* out = (float*)d_out;

  f16* x16 = (f16*)d_ws;          // 3*NE
  f16* w16 = x16 + 3 * NE;        // 4*WE
  f16* Qp  = w16 + 4 * WE;        // NE, pre-scaled
  f16* Kp  = Qp + NE;             // NE
  f16* VpT = Kp + NE;             // NE (768, L)
  f16* AO  = VpT + NE;            // NE
  // total 48.8 MB

  const int ncvt = (int)((3 * (NE / 4) + 4 * (WE / 4)) / 256);
  cvt_all<<<ncvt, 256, 0, stream>>>(q, k, v, Wq, Wk, Wv, Wo, x16, w16);

  qkv_gemm<<<1152, 256, 0, stream>>>(x16, w16, bq, bk, bv, Qp, Kp, VpT);

  dim3 gattn(NHEADS, L_SEQ / 64);
  attn_mfma4<<<gattn, 256, 0, stream>>>(Qp, Kp, VpT, AO);

  out_gemm<<<192, 256, 0, stream>>>(AO, w16 + 3 * WE, bo, out);
}